// Round 13
// baseline (53.000 us; speedup 1.0000x reference)
//
#include <hip/hip_runtime.h>

// Problem constants
#define NN 20000
#define SS 400
#define QP 60                      // floats per (q,p) row
#define NPAIRS 10000               // n-pairs
#define JPB 64                     // n-pairs per block (one per lane)
#define NBLK ((NPAIRS + JPB - 1)/JPB)  // 157
#define NP2 (NBLK*JPB*2)           // 20096 padded n
#define GSPLIT 5                   // s chunks across gridDim.y
#define SB (SS/GSPLIT)             // 80 s per block
#define WAVES 8
#define BLK_B (WAVES*64)           // 512
#define SW (SB/WAVES)              // 10 s per wave
#define NC 5                       // q-chunks (4 qubits / 12 floats each)
#define PTF4 (JPB*30)              // 1920 float4 per block's pauli tile
#define PF4TOT (NN*QP/4)           // 300000 float4 in pauli

// ws layout (floats)
#define WS_H    0                            // heads2 r2-folded, c-major [GSPLIT][NC][SB][12]
#define WS_PT   (SS*QP)                      // 24000: pair-transposed pauli [NBLK][30][64] float4
#define WS_COV  (WS_PT + NBLK*PTF4*4)        // cov partial slots [GSPLIT][NP2] (one-shot)
#define WS_CNT  (WS_COV + GSPLIT*NP2)        // per-bx arrival counters (int)

typedef float v2f __attribute__((ext_vector_type(2)));

__device__ __forceinline__ v2f lo4(float4 f) { v2f r; r.x = f.x; r.y = f.y; return r; }
__device__ __forceinline__ v2f hi4(float4 f) { v2f r; r.x = f.z; r.y = f.w; return r; }

// prep: 157 blocks x 512. Coalesced LDS-based pauli pair-transpose (PT table:
// [k][lane] float4, 16B lane-stride -> conflict-free b128 reads in main) +
// heads/ratios echo outputs + c-major r2-folded heads table + counters/loss=0.
__global__ __launch_bounds__(512) void prep_kernel(
        const float* __restrict__ heads_param,
        const float* __restrict__ ratios_param,
        const float* __restrict__ pauli,
        float* __restrict__ out, float* __restrict__ ws) {
    __shared__ float ldsR[JPB*2*QP];   // 128 rows x 60 floats = 30 KB

    const int tid = threadIdx.x;
    const int bx  = blockIdx.x;

    // 1) Linear, fully-coalesced load of this block's 128 pauli rows
    {
        const float4* src = reinterpret_cast<const float4*>(pauli) + (size_t)bx * PTF4;
        float4* dst = reinterpret_cast<float4*>(ldsR);
        #pragma unroll
        for (int it = 0; it < 4; ++it) {
            int i = tid + it*512;
            if (i < PTF4) {
                int gi = bx*PTF4 + i;
                dst[i] = (gi < PF4TOT) ? src[i] : make_float4(0.f,0.f,0.f,0.f);
            }
        }
    }
    __syncthreads();

    // 2) Pair-interleaved PT tile, coalesced global writes
    {
        float4* pt = reinterpret_cast<float4*>(ws + WS_PT) + (size_t)bx * PTF4;
        #pragma unroll
        for (int it = 0; it < 4; ++it) {
            int i = tid + it*512;
            if (i < PTF4) {
                int k = i >> 6, l = i & 63;
                float4 v;
                v.x = ldsR[(2*l  )*QP + 2*k    ];
                v.y = ldsR[(2*l+1)*QP + 2*k    ];
                v.z = ldsR[(2*l  )*QP + 2*k + 1];
                v.w = ldsR[(2*l+1)*QP + 2*k + 1];
                pt[i] = v;
            }
        }
    }

    // 3) heads / ratios outputs + c-major r2-folded heads table + zero state
    const int gi = bx*512 + tid;
    if (gi < SS*QP) {
        int s = gi / QP;
        int k = gi - s*QP;
        float h = heads_param[gi];
        float h2 = h * h;
        out[1 + SS + gi] = h2;                         // heads output (unscaled)
        float rr = ratios_param[s];
        float v = (k < 3) ? h2 * (rr*rr) : h2;         // fold r2 into q=0 dot
        int g  = s / SB, sl = s - g*SB;
        int c  = k / 12, kk = k - c*12;
        ws[WS_H + (((size_t)g*NC + c)*SB + sl)*12 + kk] = v;  // c-major
    }
    if (gi < SS) {
        float rr = ratios_param[gi];
        out[1 + gi] = rr * rr;                         // ratios output
    }
    if (gi < NBLK) reinterpret_cast<int*>(ws + WS_CNT)[gi] = 0;  // arrival counters
    if (gi == 0) out[0] = 0.f;                         // loss accumulator base
}

// One s-step for q-chunk c: 3 uniform-address VECTOR loads of the heads chunk
// (VMEM/vmcnt pipe — NOT s_load/lgkmcnt, which would force lgkmcnt(0) drains
// of the pauli ds_reads: SMEM completes out-of-order vs DS on the shared
// counter), 15 packed ops covering (1 s, 4 q, 2 n).
#define S_STEP(A, SI)                                                   \
    do {                                                                \
        const float4* hf = reinterpret_cast<const float4*>(hc + (SI)*12); \
        float4 f0 = hf[0], f1 = hf[1], f2 = hf[2];                      \
        v2f d0 = pq0*f0.x + pq1*f0.y  + pq2*f0.z;                       \
        v2f d1 = pq3*f0.w + pq4*f1.x  + pq5*f1.y;                       \
        v2f d2 = pq6*f1.z + pq7*f1.w  + pq8*f2.x;                       \
        v2f d3 = pq9*f2.y + pq10*f2.z + pq11*f2.w;                      \
        A *= (d0*d1)*(d2*d3);                                           \
    } while (0)

// main: r12 interior + heads via VMEM broadcast. __launch_bounds__(512,2)
// lifts the 64-VGPR cap so the heads-load batches don't spill (expect ~96).
__global__ __launch_bounds__(BLK_B, 2) void main_kernel(
        const float* __restrict__ hws,   // ws + WS_H  (read-only, disjoint)
        const float4* __restrict__ pt,   // ws + WS_PT (read-only, disjoint)
        float* covp,                     // ws + WS_COV slots [GSPLIT][NP2]
        int*   cnt,                      // ws + WS_CNT
        const float* __restrict__ coeff,
        float* out) {
    __shared__ float4 ldsP[PTF4];        // 30 KB pair-transposed pauli tile
    __shared__ v2f    ldsC[WAVES][64];   // 4 KB cross-wave reduce

    const int tid  = threadIdx.x;
    const int wave = __builtin_amdgcn_readfirstlane(tid >> 6);
    const int wavev = tid >> 6;          // NOT readfirstlane: keeps heads loads
                                         // in the VMEM (vmcnt) pipe, not SMEM
    const int lane = tid & 63;
    const int g    = blockIdx.y;
    const int bx   = blockIdx.x;

    // Stage this block's pauli tile: linear copy, coalesced + conflict-free
    {
        const float4* src = pt + (size_t)bx * PTF4;
        for (int i = tid; i < PTF4; i += BLK_B) ldsP[i] = src[i];
    }
    __syncthreads();

    v2f one; one.x = 1.f; one.y = 1.f;
    v2f a0=one,a1=one,a2=one,a3=one,a4=one,a5=one,a6=one,a7=one,a8=one,a9=one;

    #pragma unroll 1    // q-phase split: 24 pauli floats live at a time
    for (int c = 0; c < NC; ++c) {
        // this wave's 10 s-rows for chunk c: 480 contiguous bytes, same address
        // across all 64 lanes -> one L1 line per load, broadcast
        const float* hc = hws + (((size_t)g*NC + c)*SB + wavev*SW)*12;
        float4 q0 = ldsP[(c*6+0)*64+lane], q1 = ldsP[(c*6+1)*64+lane];
        float4 q2 = ldsP[(c*6+2)*64+lane], q3 = ldsP[(c*6+3)*64+lane];
        float4 q4 = ldsP[(c*6+4)*64+lane], q5 = ldsP[(c*6+5)*64+lane];
        v2f pq0 = lo4(q0), pq1  = hi4(q0), pq2  = lo4(q1), pq3  = hi4(q1);
        v2f pq4 = lo4(q2), pq5  = hi4(q2), pq6  = lo4(q3), pq7  = hi4(q3);
        v2f pq8 = lo4(q4), pq9  = hi4(q4), pq10 = lo4(q5), pq11 = hi4(q5);
        S_STEP(a0, 0); S_STEP(a1, 1); S_STEP(a2, 2); S_STEP(a3, 3); S_STEP(a4, 4);
        S_STEP(a5, 5); S_STEP(a6, 6); S_STEP(a7, 7); S_STEP(a8, 8); S_STEP(a9, 9);
    }

    // Sum over this wave's s (r2 already folded in)
    v2f cv = (((a0+a1)+(a2+a3)) + ((a4+a5)+(a6+a7))) + (a8+a9);
    ldsC[wave][lane] = cv;
    __syncthreads();

    if (wave == 0) {
        v2f t = ldsC[0][lane];
        #pragma unroll
        for (int w = 1; w < WAVES; ++w) t += ldsC[w][lane];
        const int j  = bx * JPB + lane;
        const int n0 = 2 * j;
        // One-shot partial slots at the coherent point (AGENT scope = visible
        // cross-XCD; each slot written exactly once -> no RMW, no init).
        float* slot = covp + (size_t)g * NP2 + n0;
        __hip_atomic_store(slot,     t.x, __ATOMIC_RELAXED, __HIP_MEMORY_SCOPE_AGENT);
        __hip_atomic_store(slot + 1, t.y, __ATOMIC_RELAXED, __HIP_MEMORY_SCOPE_AGENT);
        // drain: both stores ack'd at coherent point before announcing arrival
        asm volatile("s_waitcnt vmcnt(0)" ::: "memory");
        int old = 0;
        if (lane == 0) old = atomicAdd(cnt + bx, 1);
        old = __shfl(old, 0);
        if (old == GSPLIT - 1) {
            // last arriver for this bx: all 5 g-partials are published
            float cs0 = 0.f, cs1 = 0.f;
            #pragma unroll
            for (int g2 = 0; g2 < GSPLIT; ++g2) {
                const float* s2 = covp + (size_t)g2 * NP2 + n0;
                cs0 += __hip_atomic_load(s2,     __ATOMIC_RELAXED, __HIP_MEMORY_SCOPE_AGENT);
                cs1 += __hip_atomic_load(s2 + 1, __ATOMIC_RELAXED, __HIP_MEMORY_SCOPE_AGENT);
            }
            float term = 0.f;
            if (n0 < NN)     { float c0 = coeff[n0];     term += (c0*c0) / cs0; }
            if (n0 + 1 < NN) { float c1 = coeff[n0 + 1]; term += (c1*c1) / cs1; }
            #pragma unroll
            for (int off = 32; off; off >>= 1) term += __shfl_down(term, off);
            if (lane == 0) atomicAdd(out, term);
        }
    }
}

extern "C" void kernel_launch(void* const* d_in, const int* in_sizes, int n_in,
                              void* d_out, int out_size, void* d_ws, size_t ws_size,
                              hipStream_t stream) {
    const float* heads_param  = (const float*)d_in[0];   // [S,Q,P]
    const float* ratios_param = (const float*)d_in[1];   // [S]
    const float* pauli        = (const float*)d_in[2];   // [N,Q,P]
    const float* coeff        = (const float*)d_in[3];   // [N]
    float* out = (float*)d_out;
    float* ws  = (float*)d_ws;

    prep_kernel<<<NBLK, 512, 0, stream>>>(heads_param, ratios_param, pauli, out, ws);
    main_kernel<<<dim3(NBLK, GSPLIT), BLK_B, 0, stream>>>(
        ws + WS_H, (const float4*)(ws + WS_PT), ws + WS_COV,
        (int*)(ws + WS_CNT), coeff, out);
}

// Round 14
// 32.808 us; speedup vs baseline: 1.6154x; 1.6154x over previous
//
#include <hip/hip_runtime.h>

// Problem constants
#define NN 20000
#define SS 400
#define QP 60                      // floats per (q,p) row
#define NPAIRS 10000               // n-pairs
#define JPB 64                     // n-pairs per block (one per lane)
#define NBLK ((NPAIRS + JPB - 1)/JPB)  // 157
#define NP2 (NBLK*JPB*2)           // 20096 padded n
#define GSPLIT 5                   // s chunks across gridDim.y
#define SB (SS/GSPLIT)             // 80 s per block
#define WAVES 8
#define BLK_B (WAVES*64)           // 512
#define SW (SB/WAVES)              // 10 s per wave
#define NC 5                       // q-chunks (4 qubits / 12 floats each)
#define PTF4 (JPB*30)              // 1920 float4 per block's pauli tile
#define PF4TOT (NN*QP/4)           // 300000 float4 in pauli

// ws layout (floats)
#define WS_H    0                            // heads2 r2-folded, c-major [GSPLIT][NC][SB][12]
#define WS_PT   (SS*QP)                      // 24000: pair-transposed pauli [NBLK][30][64] float4
#define WS_COV  (WS_PT + NBLK*PTF4*4)        // cov partial slots [GSPLIT][NP2] (one-shot)
#define WS_CNT  (WS_COV + GSPLIT*NP2)        // per-bx arrival counters (int)

typedef float v2f __attribute__((ext_vector_type(2)));

__device__ __forceinline__ v2f lo4(float4 f) { v2f r; r.x = f.x; r.y = f.y; return r; }
__device__ __forceinline__ v2f hi4(float4 f) { v2f r; r.x = f.z; r.y = f.w; return r; }

// prep: 157 blocks x 512. Coalesced LDS-based pauli pair-transpose (PT table:
// [k][lane] float4 -> perfectly coalesced per-wave GLOBAL reads in main) +
// heads/ratios echo outputs + c-major r2-folded heads table + counters/loss=0.
__global__ __launch_bounds__(512) void prep_kernel(
        const float* __restrict__ heads_param,
        const float* __restrict__ ratios_param,
        const float* __restrict__ pauli,
        float* __restrict__ out, float* __restrict__ ws) {
    __shared__ float ldsR[JPB*2*QP];   // 128 rows x 60 floats = 30 KB

    const int tid = threadIdx.x;
    const int bx  = blockIdx.x;

    // 1) Linear, fully-coalesced load of this block's 128 pauli rows
    {
        const float4* src = reinterpret_cast<const float4*>(pauli) + (size_t)bx * PTF4;
        float4* dst = reinterpret_cast<float4*>(ldsR);
        #pragma unroll
        for (int it = 0; it < 4; ++it) {
            int i = tid + it*512;
            if (i < PTF4) {
                int gi = bx*PTF4 + i;
                dst[i] = (gi < PF4TOT) ? src[i] : make_float4(0.f,0.f,0.f,0.f);
            }
        }
    }
    __syncthreads();

    // 2) Pair-interleaved PT tile, coalesced global writes
    {
        float4* pt = reinterpret_cast<float4*>(ws + WS_PT) + (size_t)bx * PTF4;
        #pragma unroll
        for (int it = 0; it < 4; ++it) {
            int i = tid + it*512;
            if (i < PTF4) {
                int k = i >> 6, l = i & 63;
                float4 v;
                v.x = ldsR[(2*l  )*QP + 2*k    ];
                v.y = ldsR[(2*l+1)*QP + 2*k    ];
                v.z = ldsR[(2*l  )*QP + 2*k + 1];
                v.w = ldsR[(2*l+1)*QP + 2*k + 1];
                pt[i] = v;
            }
        }
    }

    // 3) heads / ratios outputs + c-major r2-folded heads table + zero state
    const int gi = bx*512 + tid;
    if (gi < SS*QP) {
        int s = gi / QP;
        int k = gi - s*QP;
        float h = heads_param[gi];
        float h2 = h * h;
        out[1 + SS + gi] = h2;                         // heads output (unscaled)
        float rr = ratios_param[s];
        float v = (k < 3) ? h2 * (rr*rr) : h2;         // fold r2 into q=0 dot
        int g  = s / SB, sl = s - g*SB;
        int c  = k / 12, kk = k - c*12;
        ws[WS_H + (((size_t)g*NC + c)*SB + sl)*12 + kk] = v;  // c-major
    }
    if (gi < SS) {
        float rr = ratios_param[gi];
        out[1 + gi] = rr * rr;                         // ratios output
    }
    if (gi < NBLK) reinterpret_cast<int*>(ws + WS_CNT)[gi] = 0;  // arrival counters
    if (gi == 0) out[0] = 0.f;                         // loss accumulator base
}

// One s-step for q-chunk c: 3 wave-uniform scalar (SMEM) reads of the heads
// chunk — harmless lgkmcnt now that NO ds_reads share the counter — and
// 15 packed ops covering (1 s, 4 q, 2 n).
#define S_STEP(A, SI)                                                   \
    do {                                                                \
        const float4* hf = reinterpret_cast<const float4*>(hc + (SI)*12); \
        float4 f0 = hf[0], f1 = hf[1], f2 = hf[2];                      \
        v2f d0 = pq0*f0.x + pq1*f0.y  + pq2*f0.z;                       \
        v2f d1 = pq3*f0.w + pq4*f1.x  + pq5*f1.y;                       \
        v2f d2 = pq6*f1.z + pq7*f1.w  + pq8*f2.x;                       \
        v2f d3 = pq9*f2.y + pq10*f2.z + pq11*f2.w;                      \
        A *= (d0*d1)*(d2*d3);                                           \
    } while (0)

// main: NO LDS in the hot loop. Pauli PT read directly from L2/L3 with
// coalesced per-wave global loads (lane-indexed [k][lane] layout); heads via
// SMEM broadcast. Only 4 KB LDS (reduce) -> no LDS occupancy cap, no staging
// barrier. Finalize fused (r11/r12-proven atomic protocol).
__global__ __launch_bounds__(BLK_B) void main_kernel(
        const float* __restrict__ hws,   // ws + WS_H  (read-only, disjoint)
        const float4* __restrict__ pt,   // ws + WS_PT (read-only, disjoint)
        float* covp,                     // ws + WS_COV slots [GSPLIT][NP2]
        int*   cnt,                      // ws + WS_CNT
        const float* __restrict__ coeff,
        float* out) {
    __shared__ v2f ldsC[WAVES][64];      // 4 KB cross-wave reduce (only LDS)

    const int tid  = threadIdx.x;
    const int wave = __builtin_amdgcn_readfirstlane(tid >> 6);
    const int lane = tid & 63;
    const int g    = blockIdx.y;
    const int bx   = blockIdx.x;

    // Lane's column of the PT tile: pt[bx][k][lane], k = c*6+r
    const float4* ptb = pt + (size_t)bx * PTF4 + lane;

    v2f one; one.x = 1.f; one.y = 1.f;
    v2f a0=one,a1=one,a2=one,a3=one,a4=one,a5=one,a6=one,a7=one,a8=one,a9=one;

    #pragma unroll 1    // q-phase split: 24 pauli floats live at a time
    for (int c = 0; c < NC; ++c) {
        // 6 coalesced global loads (1 KB/wave each) from L2/L3-resident PT
        float4 q0 = ptb[(c*6+0)*64], q1 = ptb[(c*6+1)*64];
        float4 q2 = ptb[(c*6+2)*64], q3 = ptb[(c*6+3)*64];
        float4 q4 = ptb[(c*6+4)*64], q5 = ptb[(c*6+5)*64];
        // this wave's 10 s-rows for chunk c: 480 contiguous bytes (SMEM)
        const float* hc = hws + (((size_t)g*NC + c)*SB + wave*SW)*12;
        v2f pq0 = lo4(q0), pq1  = hi4(q0), pq2  = lo4(q1), pq3  = hi4(q1);
        v2f pq4 = lo4(q2), pq5  = hi4(q2), pq6  = lo4(q3), pq7  = hi4(q3);
        v2f pq8 = lo4(q4), pq9  = hi4(q4), pq10 = lo4(q5), pq11 = hi4(q5);
        S_STEP(a0, 0); S_STEP(a1, 1); S_STEP(a2, 2); S_STEP(a3, 3); S_STEP(a4, 4);
        S_STEP(a5, 5); S_STEP(a6, 6); S_STEP(a7, 7); S_STEP(a8, 8); S_STEP(a9, 9);
    }

    // Sum over this wave's s (r2 already folded in)
    v2f cv = (((a0+a1)+(a2+a3)) + ((a4+a5)+(a6+a7))) + (a8+a9);
    ldsC[wave][lane] = cv;
    __syncthreads();

    if (wave == 0) {
        v2f t = ldsC[0][lane];
        #pragma unroll
        for (int w = 1; w < WAVES; ++w) t += ldsC[w][lane];
        const int j  = bx * JPB + lane;
        const int n0 = 2 * j;
        // One-shot partial slots at the coherent point (AGENT scope = visible
        // cross-XCD; each slot written exactly once -> no RMW, no init).
        float* slot = covp + (size_t)g * NP2 + n0;
        __hip_atomic_store(slot,     t.x, __ATOMIC_RELAXED, __HIP_MEMORY_SCOPE_AGENT);
        __hip_atomic_store(slot + 1, t.y, __ATOMIC_RELAXED, __HIP_MEMORY_SCOPE_AGENT);
        // drain: both stores ack'd at coherent point before announcing arrival
        asm volatile("s_waitcnt vmcnt(0)" ::: "memory");
        int old = 0;
        if (lane == 0) old = atomicAdd(cnt + bx, 1);
        old = __shfl(old, 0);
        if (old == GSPLIT - 1) {
            // last arriver for this bx: all 5 g-partials are published
            float cs0 = 0.f, cs1 = 0.f;
            #pragma unroll
            for (int g2 = 0; g2 < GSPLIT; ++g2) {
                const float* s2 = covp + (size_t)g2 * NP2 + n0;
                cs0 += __hip_atomic_load(s2,     __ATOMIC_RELAXED, __HIP_MEMORY_SCOPE_AGENT);
                cs1 += __hip_atomic_load(s2 + 1, __ATOMIC_RELAXED, __HIP_MEMORY_SCOPE_AGENT);
            }
            float term = 0.f;
            if (n0 < NN)     { float c0 = coeff[n0];     term += (c0*c0) / cs0; }
            if (n0 + 1 < NN) { float c1 = coeff[n0 + 1]; term += (c1*c1) / cs1; }
            #pragma unroll
            for (int off = 32; off; off >>= 1) term += __shfl_down(term, off);
            if (lane == 0) atomicAdd(out, term);
        }
    }
}

extern "C" void kernel_launch(void* const* d_in, const int* in_sizes, int n_in,
                              void* d_out, int out_size, void* d_ws, size_t ws_size,
                              hipStream_t stream) {
    const float* heads_param  = (const float*)d_in[0];   // [S,Q,P]
    const float* ratios_param = (const float*)d_in[1];   // [S]
    const float* pauli        = (const float*)d_in[2];   // [N,Q,P]
    const float* coeff        = (const float*)d_in[3];   // [N]
    float* out = (float*)d_out;
    float* ws  = (float*)d_ws;

    prep_kernel<<<NBLK, 512, 0, stream>>>(heads_param, ratios_param, pauli, out, ws);
    main_kernel<<<dim3(NBLK, GSPLIT), BLK_B, 0, stream>>>(
        ws + WS_H, (const float4*)(ws + WS_PT), ws + WS_COV,
        (int*)(ws + WS_CNT), coeff, out);
}